// Round 15
// baseline (21066.838 us; speedup 1.0000x reference)
//
#include <hip/hip_runtime.h>
#include <math.h>

typedef __attribute__((ext_vector_type(8))) _Float16 half8;
typedef __attribute__((ext_vector_type(4))) float    f32x4;
typedef unsigned long long u64;

#define NSTEP 256
#define CH    32              // steps per persistent chunk
#define NCHUNK (NSTEP/CH)
#define NB    1024
#define HID   256
#define BH    262144          // NB*HID
#define NPAN  16              // panels (64 rows each), 2 per XCD
#define LK    40              // gemm_t LDS row stride (f16)
#define LK1H  712             // W1-hi LDS row stride (f16), holds kt<22
#define LW2   520             // W2-hi LDS row stride (f16)
#define INV2K 4.8828125e-4f   // 1/2048

// persistent-kernel LDS layout (bytes)
#define W1H_OFF 0             // 32 x 712 x 2 = 45568
#define W2H_OFF 45568         // 32 x 520 x 2 = 33280 -> end 78848
#define SEQ_SMEM 79872        // forces exactly 2 blocks/CU (160KB/79.9KB = 2)

__device__ __forceinline__ float sigf(float x){ return 1.f/(1.f+expf(-x)); }
__device__ __forceinline__ void splitf(float v, _Float16& h, _Float16& l){
    h = (_Float16)v; l = (_Float16)((v - (float)h)*2048.f);
}

// ---------------------------------------------------------------------------
// Weight pre-split (transpose + fp16 hi/lo). perm=1: gate-interleaved cols.
// ---------------------------------------------------------------------------
__global__ __launch_bounds__(256)
void wsplit_k(const float* __restrict__ s0, const float* __restrict__ s1,
              const float* __restrict__ s2, int K, int N, int ldn,
              int kb1, int kb2, int perm,
              _Float16* __restrict__ oh, _Float16* __restrict__ ol)
{
    int idx = blockIdx.x*256 + threadIdx.x;
    if (idx >= N*K) return;
    int n = idx / K, k = idx - n*K;
    int jsrc = perm ? ((n&3)*256 + (n>>2)) : n;
    const float* s = (k < kb1) ? &s0[(size_t)k*ldn]
                   : (k < kb2) ? &s1[(size_t)(k-kb1)*ldn]
                               : &s2[(size_t)(k-kb2)*ldn];
    float v = s[jsrc];
    _Float16 h, l; splitf(v, h, l);
    oh[idx] = h; ol[idx] = l;
}

__global__ void wz_k(const float* __restrict__ W01, const float* __restrict__ U21,
                     const float* __restrict__ U11, float* __restrict__ wz)
{
    int k = blockIdx.x*256 + threadIdx.x;
    if (k >= 768) return;
    wz[k] = (k < 256) ? W01[(size_t)k*1025 + 1024]
          : (k < 512) ? U21[(size_t)(k-256)*1025 + 1024]
                      : U11[(size_t)(k-512)*1025 + 1024];
}

__global__ __launch_bounds__(256)
void init_k(_Float16* h1H, _Float16* h1L, _Float16* h2H, _Float16* h2L,
            float* c1g, float* c2g, unsigned* zcb)
{
    int i = blockIdx.x*256 + threadIdx.x;   // BH threads
    h1H[i] = (_Float16)0.f; h1L[i] = (_Float16)0.f;
    h2H[i] = (_Float16)0.f; h2L[i] = (_Float16)0.f;
    c1g[i] = 0.f; c2g[i] = 0.f;
    if (i < NB) zcb[i] = 1u;
}

// ---------------------------------------------------------------------------
// Tiled parallel GEMM (encoder/head) — unchanged from passing round-4 code.
// ---------------------------------------------------------------------------
template<int AIN, int AOUT, int NCOL>
__global__ __launch_bounds__(256)
void gemm_t(const float* __restrict__ Af,
            const _Float16* __restrict__ Ah_, const _Float16* __restrict__ Al_,
            const _Float16* __restrict__ Bh_, const _Float16* __restrict__ Bl_,
            const float* __restrict__ bias,
            _Float16* __restrict__ Oh, _Float16* __restrict__ Ol,
            float* __restrict__ Of)
{
    constexpr int NT = 8;     // K = 256
    __shared__ __align__(16) char smem[40960];

    const int tid  = threadIdx.x;
    const size_t R0 = (size_t)blockIdx.x*64;
    const int C0   = blockIdx.y*64;
    const int rh   = (tid>>6)&1, ch = tid>>7;
    const int lane = tid&63, lr = lane&15, kq = (lane>>4)<<3;
    const int arow = tid>>2, seg = tid&3;
    const size_t abase = (R0+arow)*256 + seg*8;
    const size_t wbase = (size_t)(C0 + (tid>>2))*256 + seg*8;

    f32x4 am[2][2], ax[2][2];
#pragma unroll
    for (int r=0;r<2;++r)
#pragma unroll
        for (int c=0;c<2;++c){ am[r][c]=(f32x4)0.f; ax[r][c]=(f32x4)0.f; }

    half8 rah, ral, rwh, rwl;
    auto load_tile = [&](int k0, half8& ah, half8& al, half8& wh, half8& wl) {
        if (AIN == 0) {
            float4 a0 = *(const float4*)(Af + abase + k0);
            float4 a1 = *(const float4*)(Af + abase + k0 + 4);
            float av[8] = {a0.x,a0.y,a0.z,a0.w,a1.x,a1.y,a1.z,a1.w};
#pragma unroll
            for (int i=0;i<8;++i){ _Float16 h,l; splitf(av[i],h,l); ah[i]=h; al[i]=l; }
        } else {
            ah = *(const half8*)(Ah_ + abase + k0);
            al = *(const half8*)(Al_ + abase + k0);
        }
        wh = *(const half8*)(Bh_ + wbase + k0);
        wl = *(const half8*)(Bl_ + wbase + k0);
    };
    auto store_tile = [&](int buf) {
        char* bs = smem + buf*20480;
        *(half8*)((_Float16*)(bs        ) + arow*LK + seg*8) = rah;
        *(half8*)((_Float16*)(bs +  5120) + arow*LK + seg*8) = ral;
        *(half8*)((_Float16*)(bs + 10240) + (tid>>2)*LK + seg*8) = rwh;
        *(half8*)((_Float16*)(bs + 15360) + (tid>>2)*LK + seg*8) = rwl;
    };

    load_tile(0, rah, ral, rwh, rwl);
    store_tile(0);

#pragma unroll 2
    for (int kb = 0; kb < NT; ++kb) {
        const int buf = kb & 1;
        half8 nah, nal, nwh, nwl;
        if (kb+1 < NT) load_tile((kb+1)*32, nah, nal, nwh, nwl);
        __syncthreads();
        const char* bs = smem + buf*20480;
        const _Float16* LAh = (const _Float16*)bs;
        const _Float16* LAl = (const _Float16*)(bs +  5120);
        const _Float16* LBh = (const _Float16*)(bs + 10240);
        const _Float16* LBl = (const _Float16*)(bs + 15360);
        half8 fah[2], fal[2], fbh[2], fbl[2];
#pragma unroll
        for (int rf=0;rf<2;++rf) {
            fah[rf] = *(const half8*)(LAh + (rh*32+rf*16+lr)*LK + kq);
            fal[rf] = *(const half8*)(LAl + (rh*32+rf*16+lr)*LK + kq);
        }
#pragma unroll
        for (int cf=0;cf<2;++cf) {
            fbh[cf] = *(const half8*)(LBh + (ch*32+cf*16+lr)*LK + kq);
            fbl[cf] = *(const half8*)(LBl + (ch*32+cf*16+lr)*LK + kq);
        }
#pragma unroll
        for (int cf=0;cf<2;++cf)
#pragma unroll
            for (int rf=0;rf<2;++rf) {
                am[rf][cf] = __builtin_amdgcn_mfma_f32_16x16x32_f16(fah[rf], fbh[cf], am[rf][cf],0,0,0);
                ax[rf][cf] = __builtin_amdgcn_mfma_f32_16x16x32_f16(fah[rf], fbl[cf], ax[rf][cf],0,0,0);
                ax[rf][cf] = __builtin_amdgcn_mfma_f32_16x16x32_f16(fal[rf], fbh[cf], ax[rf][cf],0,0,0);
            }
        if (kb+1 < NT) {
            rah=nah; ral=nal; rwh=nwh; rwl=nwl;
            store_tile((kb+1)&1);
        }
    }

#pragma unroll
    for (int cf=0;cf<2;++cf) {
        int col = C0 + ch*32 + cf*16 + lr;
        float bcol = bias[col];
#pragma unroll
        for (int rf=0;rf<2;++rf)
#pragma unroll
            for (int q=0;q<4;++q) {
                size_t row = R0 + rh*32 + rf*16 + ((lane>>4)<<2) + q;
                float v = am[rf][cf][q] + ax[rf][cf][q]*INV2K + bcol;
                if (AOUT == 0) {
                    v = fmaxf(v, 0.f);
                    _Float16 h,l; splitf(v,h,l);
                    Oh[row*NCOL + col] = h;
                    Ol[row*NCOL + col] = l;
                } else {
                    Of[row*NCOL + col] = tanhf(v);
                }
            }
    }
}

// ---------------------------------------------------------------------------
// Persistent recurrence chunk. 512 blocks x 512 thr, 2 blocks/CU (forced by
// 79.9KB LDS; grid == exact capacity so a PLAIN launch is fully co-resident —
// no cooperative API needed since we only use panel-scope atomic barriers).
// While one block spins at its panel barrier, the co-resident block (usually
// a DIFFERENT panel with phase-shifted barriers) computes -> spin hidden.
// 16 panels (64 rows) x 32 col-slices (8 hidden cols). panel = 2*XCC + bit.
// Swapped-operand MFMA; gates fully in-register; per-lane 1 hidden col.
// W1-hi(kt<22) + W2-hi LDS-resident; W1-hi tail, W1-lo, W2-lo, wz from L1/L2.
// Arithmetic order identical to rounds 10-13 (absmax must reproduce).
// ---------------------------------------------------------------------------
struct PArgs {
    const _Float16 *XeH, *XeL;
    _Float16 *EmH, *EmL;
    const _Float16 *W1h, *W1l, *W2h, *W2l;
    const float *b1, *b2, *wz, *noise;
    _Float16 *h1rH, *h1rL, *h2rH, *h2rL;  // rings [(CH+1)][BH]
    unsigned *zcb;                         // [NB] chunk-carry z
    float *c1g, *c2g;                      // [BH]
    unsigned *ctr;                         // [NCHUNK][CH*2][NPAN]
    unsigned *tick;                        // [NCHUNK][8]
    int chunk;
};

__device__ __forceinline__ void barrier_arrive(unsigned* c, int tid)
{
    __syncthreads();   // drains all waves' stores (vmcnt0) before the atomic
    if (tid == 0)
        __hip_atomic_fetch_add(c, 1u, __ATOMIC_RELAXED, __HIP_MEMORY_SCOPE_AGENT);
}
__device__ __forceinline__ void barrier_wait(unsigned* c, int tid)
{
    if (tid == 0) {
        int guard = 0;
        while (__hip_atomic_load(c, __ATOMIC_RELAXED, __HIP_MEMORY_SCOPE_AGENT) < 32u
               && guard < (1<<17)) {
            __builtin_amdgcn_s_sleep(1);
            ++guard;
        }
    }
    __syncthreads();
}

__global__ __launch_bounds__(512, 4)
void hm_pers_k(PArgs a)
{
    extern __shared__ __align__(16) char smem[];

    const int tid = threadIdx.x, wv = tid>>6, lane = tid&63;
    const int lr = lane&15, hq = lane>>4, kg8 = hq<<3;
    const int rg = wv & 3, cg = wv >> 2;          // 4 row-groups x 2 col-groups

    // ---- XCD-grounded panel/cs assignment (pan broadcast reuses W1H space) --
    unsigned* pan_sh = (unsigned*)smem;
    if (tid == 0) {
        unsigned xcc;
        asm volatile("s_getreg_b32 %0, hwreg(HW_REG_XCC_ID)" : "=s"(xcc));
        xcc &= 7u;
        unsigned slot = __hip_atomic_fetch_add(a.tick + a.chunk*8 + xcc, 1u,
                          __ATOMIC_RELAXED, __HIP_MEMORY_SCOPE_AGENT);
        pan_sh[0] = xcc*2u + (slot & 1u);         // adjacent tickets alternate panels
        pan_sh[1] = (slot >> 1) & 31u;
    }
    __syncthreads();
    const int panel = pan_sh[0], cs = pan_sh[1];
    __syncthreads();                              // done reading pan before W1H staging

    const int R0 = panel*64, hb = cs*8;
    const int row = R0 + rg*16 + lr;              // batch row owned by lane
    const size_t rbase = (size_t)row*HID;
    const int hc = hb + cg*4 + hq;                // owned hidden col

    float b1v[4], b2v[4];
#pragma unroll
    for (int q=0;q<4;++q) {
        b1v[q] = a.b1[q*256 + hc];
        b2v[q] = a.b2[q*256 + hc];
    }
    const float b1z = a.b1[1024];

    // ---- stage W1-hi kt<22 (32 cols x 88 half8) + W2-hi (32 x 64) ----
#pragma unroll
    for (int it = 0; it < 6; ++it) {
        int idx = it*512 + tid;                   // 0..3071
        if (idx < 2816) {
            int c  = idx / 88;
            int ks = idx - c*88;
            const _Float16* src = a.W1h + (size_t)(cs*32 + c)*768 + ks*8;
            *(half8*)(smem + W1H_OFF + (c*LK1H + ks*8)*2) = *(const half8*)src;
        }
    }
#pragma unroll
    for (int it = 0; it < 4; ++it) {
        int idx = it*512 + tid;                   // 0..2047
        int c   = idx >> 6;
        int ks  = idx & 63;
        const _Float16* src = a.W2h + (size_t)(cs*32 + c)*512 + ks*8;
        *(half8*)(smem + W2H_OFF + (c*LW2 + ks*8)*2) = *(const half8*)src;
    }
    __syncthreads();

    float c1s = a.c1g[rbase + hc];
    float c2s = a.c2g[rbase + hc];
    bool zrv = a.zcb[row] != 0u;

    const int wcol = cs*32 + cg*16 + lr;          // global W' column for fragments
    const int lcol = cg*16 + lr;                  // LDS column
    const _Float16* W1hp = a.W1h + (size_t)wcol*768 + kg8;   // kt 22,23 tail
    const _Float16* W1lp = a.W1l + (size_t)wcol*768 + kg8;
    const _Float16* W2lp = a.W2l + (size_t)wcol*512 + kg8;

    half8 pf_h[4], pf_l[4];
    // prologue: phase1(s=0) kt 0..3 from ring slot 0
#pragma unroll
    for (int kt = 0; kt < 4; ++kt) {
        pf_h[kt] = *(const half8*)(a.h1rH + rbase + kt*32 + kg8);
        pf_l[kt] = *(const half8*)(a.h1rL + rbase + kt*32 + kg8);
    }

#pragma unroll 1
    for (int s = 0; s < CH; ++s) {
        const int t = a.chunk*CH + s;
        const _Float16* h1cH = a.h1rH + (size_t)s*BH;
        const _Float16* h1cL = a.h1rL + (size_t)s*BH;
        _Float16*       h1nH = a.h1rH + (size_t)(s+1)*BH;
        _Float16*       h1nL = a.h1rL + (size_t)(s+1)*BH;
        const _Float16* h2cH = a.h2rH + (size_t)s*BH;
        const _Float16* h2cL = a.h2rL + (size_t)s*BH;
        _Float16*       h2nH = a.h2rH + (size_t)(s+1)*BH;
        _Float16*       h2nL = a.h2rL + (size_t)(s+1)*BH;
        const _Float16* xeh = a.XeH + (size_t)t*BH;
        const _Float16* xel = a.XeL + (size_t)t*BH;

        auto ld1 = [&](int kt, half8& h, half8& l){
            const int k0 = kt*32;
            if (k0 < 256)      { h = *(const half8*)(h1cH + rbase + k0 + kg8);
                                 l = *(const half8*)(h1cL + rbase + k0 + kg8); }
            else if (k0 < 512) { h = *(const half8*)(h2cH + rbase + (k0-256) + kg8);
                                 l = *(const half8*)(h2cL + rbase + (k0-256) + kg8); }
            else               { h = *(const half8*)(xeh + rbase + (k0-512) + kg8);
                                 l = *(const half8*)(xel + rbase + (k0-512) + kg8); }
        };
        auto ld2 = [&](int kt, half8& h, half8& l){
            const int k0 = kt*32;
            if (k0 < 256) { h = *(const half8*)(h2cH + rbase + k0 + kg8);
                            l = *(const half8*)(h2cL + rbase + k0 + kg8); }
            else          { h = *(const half8*)(h1nH + rbase + (k0-256) + kg8);
                            l = *(const half8*)(h1nL + rbase + (k0-256) + kg8); }
        };

        // ================ phase 1: fs1 = [h1 | z*h2 | xe] @ W1 ==============
        f32x4 am = (f32x4)0.f, ax = (f32x4)0.f;
        float zacc = 0.f;

#pragma unroll
        for (int kt = 0; kt < 24; ++kt) {
            half8 sh = pf_h[kt&3], sl = pf_l[kt&3];
            if (kt+4 < 24) ld1(kt+4, pf_h[kt&3], pf_l[kt&3]);
            if (kt >= 8 && kt < 16 && !zrv) { sh = half8{}; sl = half8{}; }
#pragma unroll
            for (int i = 0; i < 8; ++i)
                zacc = fmaf((float)sh[i] + (float)sl[i]*INV2K,
                            a.wz[kt*32 + kg8 + i], zacc);
            half8 wh;
            if (kt < 22)
                wh = *(const half8*)((const _Float16*)(smem + W1H_OFF)
                                     + lcol*LK1H + kt*32 + kg8);
            else
                wh = *(const half8*)(W1hp + kt*32);
            half8 wl = *(const half8*)(W1lp + kt*32);
            am = __builtin_amdgcn_mfma_f32_16x16x32_f16(wh, sh, am,0,0,0);
            ax = __builtin_amdgcn_mfma_f32_16x16x32_f16(wl, sh, ax,0,0,0);
            ax = __builtin_amdgcn_mfma_f32_16x16x32_f16(wh, sl, ax,0,0,0);
        }
        zacc += __shfl_xor(zacc, 16);
        zacc += __shfl_xor(zacc, 32);

        float fsz = zacc + b1z;
        float zh = fminf(fmaxf((0.1f*fsz + 1.f)*0.5f, 0.05f), 0.95f);
        const bool znv = a.noise[(size_t)t*NB + row] < zh;

        // in-register gate combine + h1 update (q = gate)
        {
            float v0 = am[0] + ax[0]*INV2K + b1v[0];
            float v1 = am[1] + ax[1]*INV2K + b1v[1];
            float v2 = am[2] + ax[2]*INV2K + b1v[2];
            float v3 = am[3] + ax[3]*INV2K + b1v[3];
            float f = sigf(v0), i = sigf(v1), o = sigf(v2), g = tanhf(v3);
            float cn = f*c1s + i*g;
            c1s = cn;
            float hn = o*tanhf(cn);
            _Float16 hh, hl; splitf(hn, hh, hl);
            h1nH[rbase + hc] = hh; h1nL[rbase + hc] = hl;
            if (s == CH-1) { a.h1rH[rbase + hc] = hh; a.h1rL[rbase + hc] = hl; }
        }
        if (s == CH-1 && cg == 0 && hq == 0) a.zcb[row] = znv ? 1u : 0u;

        unsigned* b1c = a.ctr + ((size_t)(a.chunk*CH + s)*2 + 0)*NPAN + panel;
        barrier_arrive(b1c, tid);

        // -------- window 1: p2a h2-region (legal: h2c from step s-1) --------
        am = (f32x4)0.f; ax = (f32x4)0.f;
#pragma unroll
        for (int kt = 0; kt < 4; ++kt) ld2(kt, pf_h[kt], pf_l[kt]);
#pragma unroll
        for (int kt = 0; kt < 8; ++kt) {
            half8 sh = pf_h[kt&3], sl = pf_l[kt&3];
            if (kt+4 < 8) ld2(kt+4, pf_h[kt&3], pf_l[kt&3]);
            half8 wh = *(const half8*)((const _Float16*)(smem + W2H_OFF)
                                       + lcol*LW2 + kt*32 + kg8);
            half8 wl = *(const half8*)(W2lp + kt*32);
            am = __builtin_amdgcn_mfma_f32_16x16x32_f16(wh, sh, am,0,0,0);
            ax = __builtin_amdgcn_mfma_f32_16x16x32_f16(wl, sh, ax,0,0,0);
            ax = __builtin_amdgcn_mfma_f32_16x16x32_f16(wh, sl, ax,0,0,0);
        }
        barrier_wait(b1c, tid);

        // -------- phase 2b: h1n-region (needs all panel blocks' h1n) --------
#pragma unroll
        for (int kt = 8; kt < 12; ++kt) ld2(kt, pf_h[kt&3], pf_l[kt&3]);
#pragma unroll
        for (int kt = 8; kt < 16; ++kt) {
            half8 sh = pf_h[kt&3], sl = pf_l[kt&3];
            if (kt+4 < 16) ld2(kt+4, pf_h[kt&3], pf_l[kt&3]);
            if (!znv) { sh = half8{}; sl = half8{}; }
            half8 wh = *(const half8*)((const _Float16*)(smem + W2H_OFF)
                                       + lcol*LW2 + kt*32 + kg8);
            half8 wl = *(const half8*)(W2lp + kt*32);
            am = __builtin_amdgcn_mfma_f32_16x16x32_f16(wh, sh, am,0,0,0);
            ax = __builtin_amdgcn_mfma_f32_16x16x32_f16(wl, sh, ax,0,0,0);
            ax = __builtin_amdgcn_mfma_f32_16x16x32_f16(wh, sl, ax,0,0,0);
        }

        // epilogue 2 (in-register; znv is per-lane-row)
        {
            float v0 = am[0] + ax[0]*INV2K + b2v[0];
            float v1 = am[1] + ax[1]*INV2K + b2v[1];
            float v2 = am[2] + ax[2]*INV2K + b2v[2];
            float v3 = am[3] + ax[3]*INV2K + b2v[3];
            float f = sigf(v0), i = sigf(v1), o = sigf(v2), g = tanhf(v3);
            float cn = znv ? (f*c2s + i*g) : c2s;
            c2s = cn;
            float hn = o*tanhf(cn);
            _Float16 hh, hl; splitf(hn, hh, hl);
            h2nH[rbase + hc] = hh; h2nL[rbase + hc] = hl;
            a.EmH[(size_t)t*BH + rbase + hc] = hh;
            a.EmL[(size_t)t*BH + rbase + hc] = hl;
            if (s == CH-1) { a.h2rH[rbase + hc] = hh; a.h2rL[rbase + hc] = hl; }
        }
        zrv = znv;   // carry z in-register to next step

        unsigned* b2c = a.ctr + ((size_t)(a.chunk*CH + s)*2 + 1)*NPAN + panel;
        barrier_arrive(b2c, tid);
        if (s+1 < CH) {
            // window 2: next step's h1 prefetch (h1n stable since barrier1)
#pragma unroll
            for (int kt = 0; kt < 4; ++kt) {
                pf_h[kt] = *(const half8*)(h1nH + rbase + kt*32 + kg8);
                pf_l[kt] = *(const half8*)(h1nL + rbase + kt*32 + kg8);
            }
        }
        barrier_wait(b2c, tid);
    }

    // carry c across chunk boundary
    a.c1g[rbase + hc] = c1s;
    a.c2g[rbase + hc] = c2s;
}

// ---------------------------------------------------------------------------
extern "C" void kernel_launch(void* const* d_in, const int* in_sizes, int n_in,
                              void* d_out, int out_size, void* d_ws, size_t ws_size,
                              hipStream_t stream)
{
    const float* x     = (const float*)d_in[0];
    const float* n1    = (const float*)d_in[1];
    const float* We1   = (const float*)d_in[3];
    const float* be1   = (const float*)d_in[4];
    const float* We2   = (const float*)d_in[5];
    const float* be2   = (const float*)d_in[6];
    const float* U11_1 = (const float*)d_in[7];
    const float* U21_1 = (const float*)d_in[8];
    const float* W01_1 = (const float*)d_in[9];
    const float* b1    = (const float*)d_in[10];
    const float* U11_2 = (const float*)d_in[11];
    const float* W01_2 = (const float*)d_in[12];
    const float* b2    = (const float*)d_in[13];
    const float* Wh    = (const float*)d_in[14];
    const float* bh    = (const float*)d_in[15];
    const float* Wp    = (const float*)d_in[16];
    const float* bp_   = (const float*)d_in[17];
    float* out = (float*)d_out;

    char* p = (char*)d_ws;
    auto alloc = [&](size_t bytes){ char* q = p; p += (bytes + 255) & ~(size_t)255; return q; };
    _Float16* XeH  = (_Float16*)alloc((size_t)NSTEP*BH*2);
    _Float16* XeL  = (_Float16*)alloc((size_t)NSTEP*BH*2);
    _Float16* EmH  = (_Float16*)alloc((size_t)NSTEP*BH*2);
    _Float16* EmL  = (_Float16*)alloc((size_t)NSTEP*BH*2);
    _Float16* Wt1h = (_Float16*)alloc((size_t)1024*768*2);
    _Float16* Wt1l = (_Float16*)alloc((size_t)1024*768*2);
    _Float16* Wt2h = (_Float16*)alloc((size_t)1024*512*2);
    _Float16* Wt2l = (_Float16*)alloc((size_t)1024*512*2);
    _Float16* We1h = (_Float16*)alloc(256*256*2);
    _Float16* We1l = (_Float16*)alloc(256*256*2);
    _Float16* We2h = (_Float16*)alloc(256*256*2);
    _Float16* We2l = (_Float16*)alloc(256*256*2);
    _Float16* Whh  = (_Float16*)alloc(256*256*2);
    _Float16* Whl  = (_Float16*)alloc(256*256*2);
    _Float16* Wph  = (_Float16*)alloc(64*256*2);
    _Float16* Wpl  = (_Float16*)alloc(64*256*2);
    float*    wz1  = (float*)alloc(768*4);
    _Float16* h1rH = (_Float16*)alloc((size_t)(CH+1)*BH*2);
    _Float16* h1rL = (_Float16*)alloc((size_t)(CH+1)*BH*2);
    _Float16* h2rH = (_Float16*)alloc((size_t)(CH+1)*BH*2);
    _Float16* h2rL = (_Float16*)alloc((size_t)(CH+1)*BH*2);
    unsigned* zcb  = (unsigned*)alloc(NB*4);
    float*    c1g  = (float*)alloc((size_t)BH*4);
    float*    c2g  = (float*)alloc((size_t)BH*4);
    unsigned* ctr  = (unsigned*)alloc((size_t)NCHUNK*CH*2*NPAN*4);
    unsigned* tick = (unsigned*)alloc((size_t)NCHUNK*8*4);
    if (ws_size < (size_t)(p - (char*)d_ws)) return;

    _Float16* TmpH = EmH; _Float16* TmpL = EmL;   // encoder temp (Em dead then)
    _Float16* TpH  = XeH; _Float16* TpL  = XeL;   // head temp (Xe dead then)

    // ---- prep ----
    wsplit_k<<<dim3(3072), 256, 0, stream>>>(W01_1, U21_1, U11_1, 768, 1024, 1025, 256, 512, 1, Wt1h, Wt1l);
    wsplit_k<<<dim3(2048), 256, 0, stream>>>(W01_2, U11_2, nullptr, 512, 1024, 1025, 256, 512, 1, Wt2h, Wt2l);
    wsplit_k<<<dim3(256),  256, 0, stream>>>(We1, nullptr, nullptr, 256, 256, 256, 256, 256, 0, We1h, We1l);
    wsplit_k<<<dim3(256),  256, 0, stream>>>(We2, nullptr, nullptr, 256, 256, 256, 256, 256, 0, We2h, We2l);
    wsplit_k<<<dim3(256),  256, 0, stream>>>(Wh,  nullptr, nullptr, 256, 256, 256, 256, 256, 0, Whh,  Whl);
    wsplit_k<<<dim3(64),   256, 0, stream>>>(Wp,  nullptr, nullptr, 256, 64, 64, 256, 256, 0, Wph, Wpl);
    wz_k<<<dim3(3), 256, 0, stream>>>(W01_1, U21_1, U11_1, wz1);
    init_k<<<dim3(1024), 256, 0, stream>>>(h1rH, h1rL, h2rH, h2rL, c1g, c2g, zcb);
    (void)hipMemsetAsync(ctr, 0, (size_t)NCHUNK*CH*2*NPAN*4, stream);
    (void)hipMemsetAsync(tick, 0, (size_t)NCHUNK*8*4, stream);

    // ---- encoder: xe = relu(relu(x@We1)@We2) -> Xe ----
    for (int c = 0; c < 8; ++c) {
        size_t ro = (size_t)c*32*BH;
        gemm_t<0,0,256><<<dim3(512,4), 256, 0, stream>>>(
            x + ro, nullptr, nullptr, We1h, We1l, be1, TmpH, TmpL, nullptr);
        gemm_t<1,0,256><<<dim3(512,4), 256, 0, stream>>>(
            nullptr, TmpH, TmpL, We2h, We2l, be2, XeH + ro, XeL + ro, nullptr);
    }

    // ---- recurrence: 8 persistent chunks, PLAIN launch (512 blocks = exact
    // 2-blocks/CU capacity; no grid-wide sync used, so coop API unnecessary —
    // the 512-block cooperative launch was rejected by the runtime in r14) ----
    (void)hipFuncSetAttribute((const void*)hm_pers_k,
        hipFuncAttributeMaxDynamicSharedMemorySize, SEQ_SMEM);
    PArgs pa;
    pa.XeH = XeH; pa.XeL = XeL; pa.EmH = EmH; pa.EmL = EmL;
    pa.W1h = Wt1h; pa.W1l = Wt1l; pa.W2h = Wt2h; pa.W2l = Wt2l;
    pa.b1 = b1; pa.b2 = b2; pa.wz = wz1; pa.noise = n1;
    pa.h1rH = h1rH; pa.h1rL = h1rL; pa.h2rH = h2rH; pa.h2rL = h2rL;
    pa.zcb = zcb; pa.c1g = c1g; pa.c2g = c2g; pa.ctr = ctr; pa.tick = tick;
    for (int c = 0; c < NCHUNK; ++c) {
        pa.chunk = c;
        hm_pers_k<<<dim3(512), dim3(512), SEQ_SMEM, stream>>>(pa);
    }

    // ---- head: out = tanh(relu(emb@Wh)@Wp) ----
    for (int c = 0; c < 8; ++c) {
        size_t ro = (size_t)c*32*BH;
        gemm_t<1,0,256><<<dim3(512,4), 256, 0, stream>>>(
            nullptr, EmH + ro, EmL + ro, Whh, Whl, bh, TpH, TpL, nullptr);
        gemm_t<1,1,64><<<dim3(512,1), 256, 0, stream>>>(
            nullptr, TpH, TpL, Wph, Wpl, bp_, nullptr, nullptr,
            out + (size_t)c*32*NB*64);
    }
}

// Round 16
// 20478.566 us; speedup vs baseline: 1.0287x; 1.0287x over previous
//
#include <hip/hip_runtime.h>
#include <math.h>

typedef __attribute__((ext_vector_type(8))) _Float16 half8;
typedef __attribute__((ext_vector_type(4))) float    f32x4;
typedef unsigned long long u64;

#define NSTEP 256
#define CH    32              // steps per persistent chunk
#define NCHUNK (NSTEP/CH)
#define NB    1024
#define HID   256
#define BH    262144          // NB*HID
#define NPAN  16              // panels (64 rows each), 2 per XCD
#define LK    40              // gemm_t LDS row stride (f16)
#define LK1H  712             // W1-hi LDS row stride (f16), holds kt<22
#define LW2   520             // W2-hi LDS row stride (f16)
#define INV2K 4.8828125e-4f   // 1/2048

// persistent-kernel LDS layout (bytes)
#define W1H_OFF 0             // 32 x 712 x 2 = 45568
#define W2H_OFF 45568         // 32 x 520 x 2 = 33280 -> end 78848
#define SEQ_SMEM 79872        // forces exactly 2 blocks/CU

__device__ __forceinline__ float sigf(float x){ return 1.f/(1.f+expf(-x)); }
__device__ __forceinline__ void splitf(float v, _Float16& h, _Float16& l){
    h = (_Float16)v; l = (_Float16)((v - (float)h)*2048.f);
}

// ---------------------------------------------------------------------------
// Weight pre-split (transpose + fp16 hi/lo). perm=1: gate-interleaved cols.
// ---------------------------------------------------------------------------
__global__ __launch_bounds__(256)
void wsplit_k(const float* __restrict__ s0, const float* __restrict__ s1,
              const float* __restrict__ s2, int K, int N, int ldn,
              int kb1, int kb2, int perm,
              _Float16* __restrict__ oh, _Float16* __restrict__ ol)
{
    int idx = blockIdx.x*256 + threadIdx.x;
    if (idx >= N*K) return;
    int n = idx / K, k = idx - n*K;
    int jsrc = perm ? ((n&3)*256 + (n>>2)) : n;
    const float* s = (k < kb1) ? &s0[(size_t)k*ldn]
                   : (k < kb2) ? &s1[(size_t)(k-kb1)*ldn]
                               : &s2[(size_t)(k-kb2)*ldn];
    float v = s[jsrc];
    _Float16 h, l; splitf(v, h, l);
    oh[idx] = h; ol[idx] = l;
}

__global__ void wz_k(const float* __restrict__ W01, const float* __restrict__ U21,
                     const float* __restrict__ U11, float* __restrict__ wz)
{
    int k = blockIdx.x*256 + threadIdx.x;
    if (k >= 768) return;
    wz[k] = (k < 256) ? W01[(size_t)k*1025 + 1024]
          : (k < 512) ? U21[(size_t)(k-256)*1025 + 1024]
                      : U11[(size_t)(k-512)*1025 + 1024];
}

__global__ __launch_bounds__(256)
void init_k(_Float16* h1H, _Float16* h1L, _Float16* h2H, _Float16* h2L,
            float* c1g, float* c2g, unsigned* zcb)
{
    int i = blockIdx.x*256 + threadIdx.x;   // BH threads
    h1H[i] = (_Float16)0.f; h1L[i] = (_Float16)0.f;
    h2H[i] = (_Float16)0.f; h2L[i] = (_Float16)0.f;
    c1g[i] = 0.f; c2g[i] = 0.f;
    if (i < NB) zcb[i] = 1u;
}

// ---------------------------------------------------------------------------
// Tiled parallel GEMM (encoder/head) — unchanged from passing round-4 code.
// ---------------------------------------------------------------------------
template<int AIN, int AOUT, int NCOL>
__global__ __launch_bounds__(256)
void gemm_t(const float* __restrict__ Af,
            const _Float16* __restrict__ Ah_, const _Float16* __restrict__ Al_,
            const _Float16* __restrict__ Bh_, const _Float16* __restrict__ Bl_,
            const float* __restrict__ bias,
            _Float16* __restrict__ Oh, _Float16* __restrict__ Ol,
            float* __restrict__ Of)
{
    constexpr int NT = 8;     // K = 256
    __shared__ __align__(16) char smem[40960];

    const int tid  = threadIdx.x;
    const size_t R0 = (size_t)blockIdx.x*64;
    const int C0   = blockIdx.y*64;
    const int rh   = (tid>>6)&1, ch = tid>>7;
    const int lane = tid&63, lr = lane&15, kq = (lane>>4)<<3;
    const int arow = tid>>2, seg = tid&3;
    const size_t abase = (R0+arow)*256 + seg*8;
    const size_t wbase = (size_t)(C0 + (tid>>2))*256 + seg*8;

    f32x4 am[2][2], ax[2][2];
#pragma unroll
    for (int r=0;r<2;++r)
#pragma unroll
        for (int c=0;c<2;++c){ am[r][c]=(f32x4)0.f; ax[r][c]=(f32x4)0.f; }

    half8 rah, ral, rwh, rwl;
    auto load_tile = [&](int k0, half8& ah, half8& al, half8& wh, half8& wl) {
        if (AIN == 0) {
            float4 a0 = *(const float4*)(Af + abase + k0);
            float4 a1 = *(const float4*)(Af + abase + k0 + 4);
            float av[8] = {a0.x,a0.y,a0.z,a0.w,a1.x,a1.y,a1.z,a1.w};
#pragma unroll
            for (int i=0;i<8;++i){ _Float16 h,l; splitf(av[i],h,l); ah[i]=h; al[i]=l; }
        } else {
            ah = *(const half8*)(Ah_ + abase + k0);
            al = *(const half8*)(Al_ + abase + k0);
        }
        wh = *(const half8*)(Bh_ + wbase + k0);
        wl = *(const half8*)(Bl_ + wbase + k0);
    };
    auto store_tile = [&](int buf) {
        char* bs = smem + buf*20480;
        *(half8*)((_Float16*)(bs        ) + arow*LK + seg*8) = rah;
        *(half8*)((_Float16*)(bs +  5120) + arow*LK + seg*8) = ral;
        *(half8*)((_Float16*)(bs + 10240) + (tid>>2)*LK + seg*8) = rwh;
        *(half8*)((_Float16*)(bs + 15360) + (tid>>2)*LK + seg*8) = rwl;
    };

    load_tile(0, rah, ral, rwh, rwl);
    store_tile(0);

#pragma unroll 2
    for (int kb = 0; kb < NT; ++kb) {
        const int buf = kb & 1;
        half8 nah, nal, nwh, nwl;
        if (kb+1 < NT) load_tile((kb+1)*32, nah, nal, nwh, nwl);
        __syncthreads();
        const char* bs = smem + buf*20480;
        const _Float16* LAh = (const _Float16*)bs;
        const _Float16* LAl = (const _Float16*)(bs +  5120);
        const _Float16* LBh = (const _Float16*)(bs + 10240);
        const _Float16* LBl = (const _Float16*)(bs + 15360);
        half8 fah[2], fal[2], fbh[2], fbl[2];
#pragma unroll
        for (int rf=0;rf<2;++rf) {
            fah[rf] = *(const half8*)(LAh + (rh*32+rf*16+lr)*LK + kq);
            fal[rf] = *(const half8*)(LAl + (rh*32+rf*16+lr)*LK + kq);
        }
#pragma unroll
        for (int cf=0;cf<2;++cf) {
            fbh[cf] = *(const half8*)(LBh + (ch*32+cf*16+lr)*LK + kq);
            fbl[cf] = *(const half8*)(LBl + (ch*32+cf*16+lr)*LK + kq);
        }
#pragma unroll
        for (int cf=0;cf<2;++cf)
#pragma unroll
            for (int rf=0;rf<2;++rf) {
                am[rf][cf] = __builtin_amdgcn_mfma_f32_16x16x32_f16(fah[rf], fbh[cf], am[rf][cf],0,0,0);
                ax[rf][cf] = __builtin_amdgcn_mfma_f32_16x16x32_f16(fah[rf], fbl[cf], ax[rf][cf],0,0,0);
                ax[rf][cf] = __builtin_amdgcn_mfma_f32_16x16x32_f16(fal[rf], fbh[cf], ax[rf][cf],0,0,0);
            }
        if (kb+1 < NT) {
            rah=nah; ral=nal; rwh=nwh; rwl=nwl;
            store_tile((kb+1)&1);
        }
    }

#pragma unroll
    for (int cf=0;cf<2;++cf) {
        int col = C0 + ch*32 + cf*16 + lr;
        float bcol = bias[col];
#pragma unroll
        for (int rf=0;rf<2;++rf)
#pragma unroll
            for (int q=0;q<4;++q) {
                size_t row = R0 + rh*32 + rf*16 + ((lane>>4)<<2) + q;
                float v = am[rf][cf][q] + ax[rf][cf][q]*INV2K + bcol;
                if (AOUT == 0) {
                    v = fmaxf(v, 0.f);
                    _Float16 h,l; splitf(v,h,l);
                    Oh[row*NCOL + col] = h;
                    Ol[row*NCOL + col] = l;
                } else {
                    Of[row*NCOL + col] = tanhf(v);
                }
            }
    }
}

// ---------------------------------------------------------------------------
// Persistent recurrence chunk. 512 blocks x 512 thr, 2 blocks/CU.
// 16 panels (64 rows) x 32 col-slices. panel = 2*XCC + (slot>>5): dispatch
// fills all 32 CUs (pass 1, slots 0-31 -> panel A) before doubling up
// (pass 2, slots 32-63 -> panel B) => each CU hosts one A-block + one
// B-block with INDEPENDENT barriers -> spin hidden under the other's
// compute. (r15 used slot&1: both co-resident blocks were the SAME panel.)
// Swapped-operand MFMA; gates fully in-register; per-lane 1 hidden col.
// Arithmetic identical to r15 (absmax must reproduce).
// ---------------------------------------------------------------------------
struct PArgs {
    const _Float16 *XeH, *XeL;
    _Float16 *EmH, *EmL;
    const _Float16 *W1h, *W1l, *W2h, *W2l;
    const float *b1, *b2, *wz, *noise;
    _Float16 *h1rH, *h1rL, *h2rH, *h2rL;  // rings [(CH+1)][BH]
    unsigned *zcb;                         // [NB] chunk-carry z
    float *c1g, *c2g;                      // [BH]
    unsigned *ctr;                         // [NCHUNK][CH*2][NPAN]
    unsigned *tick;                        // [NCHUNK][8]
    int chunk;
};

__device__ __forceinline__ void barrier_arrive(unsigned* c, int tid)
{
    __syncthreads();   // drains all waves' stores (vmcnt0) before the atomic
    if (tid == 0)
        __hip_atomic_fetch_add(c, 1u, __ATOMIC_RELAXED, __HIP_MEMORY_SCOPE_AGENT);
}
__device__ __forceinline__ void barrier_wait(unsigned* c, int tid)
{
    if (tid == 0) {
        int guard = 0;
        while (__hip_atomic_load(c, __ATOMIC_RELAXED, __HIP_MEMORY_SCOPE_AGENT) < 32u
               && guard < (1<<17)) {
            __builtin_amdgcn_s_sleep(1);
            ++guard;
        }
    }
    __syncthreads();
}

__global__ __launch_bounds__(512, 4)
void hm_pers_k(PArgs a)
{
    extern __shared__ __align__(16) char smem[];

    const int tid = threadIdx.x, wv = tid>>6, lane = tid&63;
    const int lr = lane&15, hq = lane>>4, kg8 = hq<<3;
    const int rg = wv & 3, cg = wv >> 2;          // 4 row-groups x 2 col-groups

    // ---- XCD-grounded panel/cs assignment ----
    unsigned* pan_sh = (unsigned*)smem;
    if (tid == 0) {
        unsigned xcc;
        asm volatile("s_getreg_b32 %0, hwreg(HW_REG_XCC_ID)" : "=s"(xcc));
        xcc &= 7u;
        unsigned slot = __hip_atomic_fetch_add(a.tick + a.chunk*8 + xcc, 1u,
                          __ATOMIC_RELAXED, __HIP_MEMORY_SCOPE_AGENT);
        pan_sh[0] = xcc*2u + ((slot >> 5) & 1u);  // pass 1 -> panel A, pass 2 -> B
        pan_sh[1] = slot & 31u;
    }
    __syncthreads();
    const int panel = pan_sh[0], cs = pan_sh[1];
    __syncthreads();                              // done reading pan before W1H staging

    const int R0 = panel*64, hb = cs*8;
    const int row = R0 + rg*16 + lr;              // batch row owned by lane
    const size_t rbase = (size_t)row*HID;
    const int hc = hb + cg*4 + hq;                // owned hidden col

    float b1v[4], b2v[4];
#pragma unroll
    for (int q=0;q<4;++q) {
        b1v[q] = a.b1[q*256 + hc];
        b2v[q] = a.b2[q*256 + hc];
    }
    const float b1z = a.b1[1024];

    // ---- stage W1-hi kt<22 (32 cols x 88 half8) + W2-hi (32 x 64) ----
#pragma unroll
    for (int it = 0; it < 6; ++it) {
        int idx = it*512 + tid;                   // 0..3071
        if (idx < 2816) {
            int c  = idx / 88;
            int ks = idx - c*88;
            const _Float16* src = a.W1h + (size_t)(cs*32 + c)*768 + ks*8;
            *(half8*)(smem + W1H_OFF + (c*LK1H + ks*8)*2) = *(const half8*)src;
        }
    }
#pragma unroll
    for (int it = 0; it < 4; ++it) {
        int idx = it*512 + tid;                   // 0..2047
        int c   = idx >> 6;
        int ks  = idx & 63;
        const _Float16* src = a.W2h + (size_t)(cs*32 + c)*512 + ks*8;
        *(half8*)(smem + W2H_OFF + (c*LW2 + ks*8)*2) = *(const half8*)src;
    }
    __syncthreads();

    float c1s = a.c1g[rbase + hc];
    float c2s = a.c2g[rbase + hc];
    bool zrv = a.zcb[row] != 0u;

    const int wcol = cs*32 + cg*16 + lr;          // global W' column for fragments
    const int lcol = cg*16 + lr;                  // LDS column
    const _Float16* W1hp = a.W1h + (size_t)wcol*768 + kg8;   // kt 22,23 tail
    const _Float16* W1lp = a.W1l + (size_t)wcol*768 + kg8;
    const _Float16* W2lp = a.W2l + (size_t)wcol*512 + kg8;

    half8 pf_h[4], pf_l[4];
    // prologue: phase1(s=0) kt 0..3 from ring slot 0
#pragma unroll
    for (int kt = 0; kt < 4; ++kt) {
        pf_h[kt] = *(const half8*)(a.h1rH + rbase + kt*32 + kg8);
        pf_l[kt] = *(const half8*)(a.h1rL + rbase + kt*32 + kg8);
    }

#pragma unroll 1
    for (int s = 0; s < CH; ++s) {
        const int t = a.chunk*CH + s;
        const _Float16* h1cH = a.h1rH + (size_t)s*BH;
        const _Float16* h1cL = a.h1rL + (size_t)s*BH;
        _Float16*       h1nH = a.h1rH + (size_t)(s+1)*BH;
        _Float16*       h1nL = a.h1rL + (size_t)(s+1)*BH;
        const _Float16* h2cH = a.h2rH + (size_t)s*BH;
        const _Float16* h2cL = a.h2rL + (size_t)s*BH;
        _Float16*       h2nH = a.h2rH + (size_t)(s+1)*BH;
        _Float16*       h2nL = a.h2rL + (size_t)(s+1)*BH;
        const _Float16* xeh = a.XeH + (size_t)t*BH;
        const _Float16* xel = a.XeL + (size_t)t*BH;

        auto ld1 = [&](int kt, half8& h, half8& l){
            const int k0 = kt*32;
            if (k0 < 256)      { h = *(const half8*)(h1cH + rbase + k0 + kg8);
                                 l = *(const half8*)(h1cL + rbase + k0 + kg8); }
            else if (k0 < 512) { h = *(const half8*)(h2cH + rbase + (k0-256) + kg8);
                                 l = *(const half8*)(h2cL + rbase + (k0-256) + kg8); }
            else               { h = *(const half8*)(xeh + rbase + (k0-512) + kg8);
                                 l = *(const half8*)(xel + rbase + (k0-512) + kg8); }
        };
        auto ld2 = [&](int kt, half8& h, half8& l){
            const int k0 = kt*32;
            if (k0 < 256) { h = *(const half8*)(h2cH + rbase + k0 + kg8);
                            l = *(const half8*)(h2cL + rbase + k0 + kg8); }
            else          { h = *(const half8*)(h1nH + rbase + (k0-256) + kg8);
                            l = *(const half8*)(h1nL + rbase + (k0-256) + kg8); }
        };

        // ================ phase 1: fs1 = [h1 | z*h2 | xe] @ W1 ==============
        f32x4 am = (f32x4)0.f, ax = (f32x4)0.f;
        float zacc = 0.f;

#pragma unroll
        for (int kt = 0; kt < 24; ++kt) {
            half8 sh = pf_h[kt&3], sl = pf_l[kt&3];
            if (kt+4 < 24) ld1(kt+4, pf_h[kt&3], pf_l[kt&3]);
            if (kt >= 8 && kt < 16 && !zrv) { sh = half8{}; sl = half8{}; }
#pragma unroll
            for (int i = 0; i < 8; ++i)
                zacc = fmaf((float)sh[i] + (float)sl[i]*INV2K,
                            a.wz[kt*32 + kg8 + i], zacc);
            half8 wh;
            if (kt < 22)
                wh = *(const half8*)((const _Float16*)(smem + W1H_OFF)
                                     + lcol*LK1H + kt*32 + kg8);
            else
                wh = *(const half8*)(W1hp + kt*32);
            half8 wl = *(const half8*)(W1lp + kt*32);
            am = __builtin_amdgcn_mfma_f32_16x16x32_f16(wh, sh, am,0,0,0);
            ax = __builtin_amdgcn_mfma_f32_16x16x32_f16(wl, sh, ax,0,0,0);
            ax = __builtin_amdgcn_mfma_f32_16x16x32_f16(wh, sl, ax,0,0,0);
        }
        zacc += __shfl_xor(zacc, 16);
        zacc += __shfl_xor(zacc, 32);

        float fsz = zacc + b1z;
        float zh = fminf(fmaxf((0.1f*fsz + 1.f)*0.5f, 0.05f), 0.95f);
        const bool znv = a.noise[(size_t)t*NB + row] < zh;

        // in-register gate combine + h1 update (q = gate)
        {
            float v0 = am[0] + ax[0]*INV2K + b1v[0];
            float v1 = am[1] + ax[1]*INV2K + b1v[1];
            float v2 = am[2] + ax[2]*INV2K + b1v[2];
            float v3 = am[3] + ax[3]*INV2K + b1v[3];
            float f = sigf(v0), i = sigf(v1), o = sigf(v2), g = tanhf(v3);
            float cn = f*c1s + i*g;
            c1s = cn;
            float hn = o*tanhf(cn);
            _Float16 hh, hl; splitf(hn, hh, hl);
            h1nH[rbase + hc] = hh; h1nL[rbase + hc] = hl;
            if (s == CH-1) { a.h1rH[rbase + hc] = hh; a.h1rL[rbase + hc] = hl; }
        }
        if (s == CH-1 && cg == 0 && hq == 0) a.zcb[row] = znv ? 1u : 0u;

        unsigned* b1c = a.ctr + ((size_t)(a.chunk*CH + s)*2 + 0)*NPAN + panel;
        barrier_arrive(b1c, tid);

        // -------- window 1: p2a h2-region (legal: h2c from step s-1) --------
        am = (f32x4)0.f; ax = (f32x4)0.f;
#pragma unroll
        for (int kt = 0; kt < 4; ++kt) ld2(kt, pf_h[kt], pf_l[kt]);
#pragma unroll
        for (int kt = 0; kt < 8; ++kt) {
            half8 sh = pf_h[kt&3], sl = pf_l[kt&3];
            if (kt+4 < 8) ld2(kt+4, pf_h[kt&3], pf_l[kt&3]);
            half8 wh = *(const half8*)((const _Float16*)(smem + W2H_OFF)
                                       + lcol*LW2 + kt*32 + kg8);
            half8 wl = *(const half8*)(W2lp + kt*32);
            am = __builtin_amdgcn_mfma_f32_16x16x32_f16(wh, sh, am,0,0,0);
            ax = __builtin_amdgcn_mfma_f32_16x16x32_f16(wl, sh, ax,0,0,0);
            ax = __builtin_amdgcn_mfma_f32_16x16x32_f16(wh, sl, ax,0,0,0);
        }
        barrier_wait(b1c, tid);

        // -------- phase 2b: h1n-region (needs all panel blocks' h1n) --------
#pragma unroll
        for (int kt = 8; kt < 12; ++kt) ld2(kt, pf_h[kt&3], pf_l[kt&3]);
#pragma unroll
        for (int kt = 8; kt < 16; ++kt) {
            half8 sh = pf_h[kt&3], sl = pf_l[kt&3];
            if (kt+4 < 16) ld2(kt+4, pf_h[kt&3], pf_l[kt&3]);
            if (!znv) { sh = half8{}; sl = half8{}; }
            half8 wh = *(const half8*)((const _Float16*)(smem + W2H_OFF)
                                       + lcol*LW2 + kt*32 + kg8);
            half8 wl = *(const half8*)(W2lp + kt*32);
            am = __builtin_amdgcn_mfma_f32_16x16x32_f16(wh, sh, am,0,0,0);
            ax = __builtin_amdgcn_mfma_f32_16x16x32_f16(wl, sh, ax,0,0,0);
            ax = __builtin_amdgcn_mfma_f32_16x16x32_f16(wh, sl, ax,0,0,0);
        }

        // epilogue 2 (in-register; znv is per-lane-row)
        {
            float v0 = am[0] + ax[0]*INV2K + b2v[0];
            float v1 = am[1] + ax[1]*INV2K + b2v[1];
            float v2 = am[2] + ax[2]*INV2K + b2v[2];
            float v3 = am[3] + ax[3]*INV2K + b2v[3];
            float f = sigf(v0), i = sigf(v1), o = sigf(v2), g = tanhf(v3);
            float cn = znv ? (f*c2s + i*g) : c2s;
            c2s = cn;
            float hn = o*tanhf(cn);
            _Float16 hh, hl; splitf(hn, hh, hl);
            h2nH[rbase + hc] = hh; h2nL[rbase + hc] = hl;
            a.EmH[(size_t)t*BH + rbase + hc] = hh;
            a.EmL[(size_t)t*BH + rbase + hc] = hl;
            if (s == CH-1) { a.h2rH[rbase + hc] = hh; a.h2rL[rbase + hc] = hl; }
        }
        zrv = znv;   // carry z in-register to next step

        unsigned* b2c = a.ctr + ((size_t)(a.chunk*CH + s)*2 + 1)*NPAN + panel;
        barrier_arrive(b2c, tid);
        if (s+1 < CH) {
            // window 2: next step's h1 prefetch (h1n stable since barrier1)
#pragma unroll
            for (int kt = 0; kt < 4; ++kt) {
                pf_h[kt] = *(const half8*)(h1nH + rbase + kt*32 + kg8);
                pf_l[kt] = *(const half8*)(h1nL + rbase + kt*32 + kg8);
            }
        }
        barrier_wait(b2c, tid);
    }

    // carry c across chunk boundary
    a.c1g[rbase + hc] = c1s;
    a.c2g[rbase + hc] = c2s;
}

// ---------------------------------------------------------------------------
extern "C" void kernel_launch(void* const* d_in, const int* in_sizes, int n_in,
                              void* d_out, int out_size, void* d_ws, size_t ws_size,
                              hipStream_t stream)
{
    const float* x     = (const float*)d_in[0];
    const float* n1    = (const float*)d_in[1];
    const float* We1   = (const float*)d_in[3];
    const float* be1   = (const float*)d_in[4];
    const float* We2   = (const float*)d_in[5];
    const float* be2   = (const float*)d_in[6];
    const float* U11_1 = (const float*)d_in[7];
    const float* U21_1 = (const float*)d_in[8];
    const float* W01_1 = (const float*)d_in[9];
    const float* b1    = (const float*)d_in[10];
    const float* U11_2 = (const float*)d_in[11];
    const float* W01_2 = (const float*)d_in[12];
    const float* b2    = (const float*)d_in[13];
    const float* Wh    = (const float*)d_in[14];
    const float* bh    = (const float*)d_in[15];
    const float* Wp    = (const float*)d_in[16];
    const float* bp_   = (const float*)d_in[17];
    float* out = (float*)d_out;

    char* p = (char*)d_ws;
    auto alloc = [&](size_t bytes){ char* q = p; p += (bytes + 255) & ~(size_t)255; return q; };
    _Float16* XeH  = (_Float16*)alloc((size_t)NSTEP*BH*2);
    _Float16* XeL  = (_Float16*)alloc((size_t)NSTEP*BH*2);
    _Float16* EmH  = (_Float16*)alloc((size_t)NSTEP*BH*2);
    _Float16* EmL  = (_Float16*)alloc((size_t)NSTEP*BH*2);
    _Float16* Wt1h = (_Float16*)alloc((size_t)1024*768*2);
    _Float16* Wt1l = (_Float16*)alloc((size_t)1024*768*2);
    _Float16* Wt2h = (_Float16*)alloc((size_t)1024*512*2);
    _Float16* Wt2l = (_Float16*)alloc((size_t)1024*512*2);
    _Float16* We1h = (_Float16*)alloc(256*256*2);
    _Float16* We1l = (_Float16*)alloc(256*256*2);
    _Float16* We2h = (_Float16*)alloc(256*256*2);
    _Float16* We2l = (_Float16*)alloc(256*256*2);
    _Float16* Whh  = (_Float16*)alloc(256*256*2);
    _Float16* Whl  = (_Float16*)alloc(256*256*2);
    _Float16* Wph  = (_Float16*)alloc(64*256*2);
    _Float16* Wpl  = (_Float16*)alloc(64*256*2);
    float*    wz1  = (float*)alloc(768*4);
    _Float16* h1rH = (_Float16*)alloc((size_t)(CH+1)*BH*2);
    _Float16* h1rL = (_Float16*)alloc((size_t)(CH+1)*BH*2);
    _Float16* h2rH = (_Float16*)alloc((size_t)(CH+1)*BH*2);
    _Float16* h2rL = (_Float16*)alloc((size_t)(CH+1)*BH*2);
    unsigned* zcb  = (unsigned*)alloc(NB*4);
    float*    c1g  = (float*)alloc((size_t)BH*4);
    float*    c2g  = (float*)alloc((size_t)BH*4);
    unsigned* ctr  = (unsigned*)alloc((size_t)NCHUNK*CH*2*NPAN*4);
    unsigned* tick = (unsigned*)alloc((size_t)NCHUNK*8*4);
    if (ws_size < (size_t)(p - (char*)d_ws)) return;

    _Float16* TmpH = EmH; _Float16* TmpL = EmL;   // encoder temp (Em dead then)
    _Float16* TpH  = XeH; _Float16* TpL  = XeL;   // head temp (Xe dead then)

    // ---- prep ----
    wsplit_k<<<dim3(3072), 256, 0, stream>>>(W01_1, U21_1, U11_1, 768, 1024, 1025, 256, 512, 1, Wt1h, Wt1l);
    wsplit_k<<<dim3(2048), 256, 0, stream>>>(W01_2, U11_2, nullptr, 512, 1024, 1025, 256, 512, 1, Wt2h, Wt2l);
    wsplit_k<<<dim3(256),  256, 0, stream>>>(We1, nullptr, nullptr, 256, 256, 256, 256, 256, 0, We1h, We1l);
    wsplit_k<<<dim3(256),  256, 0, stream>>>(We2, nullptr, nullptr, 256, 256, 256, 256, 256, 0, We2h, We2l);
    wsplit_k<<<dim3(256),  256, 0, stream>>>(Wh,  nullptr, nullptr, 256, 256, 256, 256, 256, 0, Whh,  Whl);
    wsplit_k<<<dim3(64),   256, 0, stream>>>(Wp,  nullptr, nullptr, 256, 64, 64, 256, 256, 0, Wph, Wpl);
    wz_k<<<dim3(3), 256, 0, stream>>>(W01_1, U21_1, U11_1, wz1);
    init_k<<<dim3(1024), 256, 0, stream>>>(h1rH, h1rL, h2rH, h2rL, c1g, c2g, zcb);
    (void)hipMemsetAsync(ctr, 0, (size_t)NCHUNK*CH*2*NPAN*4, stream);
    (void)hipMemsetAsync(tick, 0, (size_t)NCHUNK*8*4, stream);

    // ---- encoder: xe = relu(relu(x@We1)@We2) -> Xe ----
    for (int c = 0; c < 8; ++c) {
        size_t ro = (size_t)c*32*BH;
        gemm_t<0,0,256><<<dim3(512,4), 256, 0, stream>>>(
            x + ro, nullptr, nullptr, We1h, We1l, be1, TmpH, TmpL, nullptr);
        gemm_t<1,0,256><<<dim3(512,4), 256, 0, stream>>>(
            nullptr, TmpH, TmpL, We2h, We2l, be2, XeH + ro, XeL + ro, nullptr);
    }

    // ---- recurrence: 8 persistent chunks, PLAIN launch (512 blocks) ----
    (void)hipFuncSetAttribute((const void*)hm_pers_k,
        hipFuncAttributeMaxDynamicSharedMemorySize, SEQ_SMEM);
    PArgs pa;
    pa.XeH = XeH; pa.XeL = XeL; pa.EmH = EmH; pa.EmL = EmL;
    pa.W1h = Wt1h; pa.W1l = Wt1l; pa.W2h = Wt2h; pa.W2l = Wt2l;
    pa.b1 = b1; pa.b2 = b2; pa.wz = wz1; pa.noise = n1;
    pa.h1rH = h1rH; pa.h1rL = h1rL; pa.h2rH = h2rH; pa.h2rL = h2rL;
    pa.zcb = zcb; pa.c1g = c1g; pa.c2g = c2g; pa.ctr = ctr; pa.tick = tick;
    for (int c = 0; c < NCHUNK; ++c) {
        pa.chunk = c;
        hm_pers_k<<<dim3(512), dim3(512), SEQ_SMEM, stream>>>(pa);
    }

    // ---- head: out = tanh(relu(emb@Wh)@Wp) ----
    for (int c = 0; c < 8; ++c) {
        size_t ro = (size_t)c*32*BH;
        gemm_t<1,0,256><<<dim3(512,4), 256, 0, stream>>>(
            nullptr, EmH + ro, EmL + ro, Whh, Whl, bh, TpH, TpL, nullptr);
        gemm_t<1,1,64><<<dim3(512,1), 256, 0, stream>>>(
            nullptr, TpH, TpL, Wph, Wpl, bp_, nullptr, nullptr,
            out + (size_t)c*32*NB*64);
    }
}

// Round 17
// 8221.423 us; speedup vs baseline: 2.5624x; 2.4909x over previous
//
#include <hip/hip_runtime.h>
#include <math.h>

typedef __attribute__((ext_vector_type(8))) _Float16 half8;
typedef __attribute__((ext_vector_type(4))) float    f32x4;
typedef unsigned long long u64;

#define NSTEP 256
#define CH    32              // steps per persistent chunk
#define NCHUNK (NSTEP/CH)
#define NB    1024
#define HID   256
#define BH    262144          // NB*HID
#define LK    40              // gemm_t LDS row stride (f16)
#define LK1   776             // W1 LDS row stride (f16)
#define LW2   520             // W2 LDS row stride (f16)
#define INV2K 4.8828125e-4f   // 1/2048

// persistent-kernel LDS layout (bytes)
#define W1H_OFF 0             // 32 x 776 x 2 = 49664
#define W1L_OFF 49664
#define W2H_OFF 99328         // 32 x 520 x 2 = 33280
#define WZ_OFF  132608        // 768 x 4 = 3072
#define PAN_OFF 135680
#define SEQ_SMEM 135936       // > 80KB -> 1 block/CU -> exactly 32 blocks/XCD

__device__ __forceinline__ float sigf(float x){ return 1.f/(1.f+expf(-x)); }
__device__ __forceinline__ void splitf(float v, _Float16& h, _Float16& l){
    h = (_Float16)v; l = (_Float16)((v - (float)h)*2048.f);
}

// ---------------------------------------------------------------------------
// Weight pre-split (transpose + fp16 hi/lo). perm=1: gate-interleaved cols.
// ---------------------------------------------------------------------------
__global__ __launch_bounds__(256)
void wsplit_k(const float* __restrict__ s0, const float* __restrict__ s1,
              const float* __restrict__ s2, int K, int N, int ldn,
              int kb1, int kb2, int perm,
              _Float16* __restrict__ oh, _Float16* __restrict__ ol)
{
    int idx = blockIdx.x*256 + threadIdx.x;
    if (idx >= N*K) return;
    int n = idx / K, k = idx - n*K;
    int jsrc = perm ? ((n&3)*256 + (n>>2)) : n;
    const float* s = (k < kb1) ? &s0[(size_t)k*ldn]
                   : (k < kb2) ? &s1[(size_t)(k-kb1)*ldn]
                               : &s2[(size_t)(k-kb2)*ldn];
    float v = s[jsrc];
    _Float16 h, l; splitf(v, h, l);
    oh[idx] = h; ol[idx] = l;
}

__global__ void wz_k(const float* __restrict__ W01, const float* __restrict__ U21,
                     const float* __restrict__ U11, float* __restrict__ wz)
{
    int k = blockIdx.x*256 + threadIdx.x;
    if (k >= 768) return;
    wz[k] = (k < 256) ? W01[(size_t)k*1025 + 1024]
          : (k < 512) ? U21[(size_t)(k-256)*1025 + 1024]
                      : U11[(size_t)(k-512)*1025 + 1024];
}

__global__ __launch_bounds__(256)
void init_k(_Float16* h1H, _Float16* h1L, _Float16* h2H, _Float16* h2L,
            float* c1g, float* c2g, unsigned* zcb)
{
    int i = blockIdx.x*256 + threadIdx.x;   // BH threads
    h1H[i] = (_Float16)0.f; h1L[i] = (_Float16)0.f;
    h2H[i] = (_Float16)0.f; h2L[i] = (_Float16)0.f;
    c1g[i] = 0.f; c2g[i] = 0.f;
    if (i < NB) zcb[i] = 1u;
}

// ---------------------------------------------------------------------------
// Tiled parallel GEMM (encoder/head) — unchanged from passing round-4 code.
// ---------------------------------------------------------------------------
template<int AIN, int AOUT, int NCOL>
__global__ __launch_bounds__(256)
void gemm_t(const float* __restrict__ Af,
            const _Float16* __restrict__ Ah_, const _Float16* __restrict__ Al_,
            const _Float16* __restrict__ Bh_, const _Float16* __restrict__ Bl_,
            const float* __restrict__ bias,
            _Float16* __restrict__ Oh, _Float16* __restrict__ Ol,
            float* __restrict__ Of)
{
    constexpr int NT = 8;     // K = 256
    __shared__ __align__(16) char smem[40960];

    const int tid  = threadIdx.x;
    const size_t R0 = (size_t)blockIdx.x*64;
    const int C0   = blockIdx.y*64;
    const int rh   = (tid>>6)&1, ch = tid>>7;
    const int lane = tid&63, lr = lane&15, kq = (lane>>4)<<3;
    const int arow = tid>>2, seg = tid&3;
    const size_t abase = (R0+arow)*256 + seg*8;
    const size_t wbase = (size_t)(C0 + (tid>>2))*256 + seg*8;

    f32x4 am[2][2], ax[2][2];
#pragma unroll
    for (int r=0;r<2;++r)
#pragma unroll
        for (int c=0;c<2;++c){ am[r][c]=(f32x4)0.f; ax[r][c]=(f32x4)0.f; }

    half8 rah, ral, rwh, rwl;
    auto load_tile = [&](int k0, half8& ah, half8& al, half8& wh, half8& wl) {
        if (AIN == 0) {
            float4 a0 = *(const float4*)(Af + abase + k0);
            float4 a1 = *(const float4*)(Af + abase + k0 + 4);
            float av[8] = {a0.x,a0.y,a0.z,a0.w,a1.x,a1.y,a1.z,a1.w};
#pragma unroll
            for (int i=0;i<8;++i){ _Float16 h,l; splitf(av[i],h,l); ah[i]=h; al[i]=l; }
        } else {
            ah = *(const half8*)(Ah_ + abase + k0);
            al = *(const half8*)(Al_ + abase + k0);
        }
        wh = *(const half8*)(Bh_ + wbase + k0);
        wl = *(const half8*)(Bl_ + wbase + k0);
    };
    auto store_tile = [&](int buf) {
        char* bs = smem + buf*20480;
        *(half8*)((_Float16*)(bs        ) + arow*LK + seg*8) = rah;
        *(half8*)((_Float16*)(bs +  5120) + arow*LK + seg*8) = ral;
        *(half8*)((_Float16*)(bs + 10240) + (tid>>2)*LK + seg*8) = rwh;
        *(half8*)((_Float16*)(bs + 15360) + (tid>>2)*LK + seg*8) = rwl;
    };

    load_tile(0, rah, ral, rwh, rwl);
    store_tile(0);

#pragma unroll 2
    for (int kb = 0; kb < NT; ++kb) {
        const int buf = kb & 1;
        half8 nah, nal, nwh, nwl;
        if (kb+1 < NT) load_tile((kb+1)*32, nah, nal, nwh, nwl);
        __syncthreads();
        const char* bs = smem + buf*20480;
        const _Float16* LAh = (const _Float16*)bs;
        const _Float16* LAl = (const _Float16*)(bs +  5120);
        const _Float16* LBh = (const _Float16*)(bs + 10240);
        const _Float16* LBl = (const _Float16*)(bs + 15360);
        half8 fah[2], fal[2], fbh[2], fbl[2];
#pragma unroll
        for (int rf=0;rf<2;++rf) {
            fah[rf] = *(const half8*)(LAh + (rh*32+rf*16+lr)*LK + kq);
            fal[rf] = *(const half8*)(LAl + (rh*32+rf*16+lr)*LK + kq);
        }
#pragma unroll
        for (int cf=0;cf<2;++cf) {
            fbh[cf] = *(const half8*)(LBh + (ch*32+cf*16+lr)*LK + kq);
            fbl[cf] = *(const half8*)(LBl + (ch*32+cf*16+lr)*LK + kq);
        }
#pragma unroll
        for (int cf=0;cf<2;++cf)
#pragma unroll
            for (int rf=0;rf<2;++rf) {
                am[rf][cf] = __builtin_amdgcn_mfma_f32_16x16x32_f16(fah[rf], fbh[cf], am[rf][cf],0,0,0);
                ax[rf][cf] = __builtin_amdgcn_mfma_f32_16x16x32_f16(fah[rf], fbl[cf], ax[rf][cf],0,0,0);
                ax[rf][cf] = __builtin_amdgcn_mfma_f32_16x16x32_f16(fal[rf], fbh[cf], ax[rf][cf],0,0,0);
            }
        if (kb+1 < NT) {
            rah=nah; ral=nal; rwh=nwh; rwl=nwl;
            store_tile((kb+1)&1);
        }
    }

#pragma unroll
    for (int cf=0;cf<2;++cf) {
        int col = C0 + ch*32 + cf*16 + lr;
        float bcol = bias[col];
#pragma unroll
        for (int rf=0;rf<2;++rf)
#pragma unroll
            for (int q=0;q<4;++q) {
                size_t row = R0 + rh*32 + rf*16 + ((lane>>4)<<2) + q;
                float v = am[rf][cf][q] + ax[rf][cf][q]*INV2K + bcol;
                if (AOUT == 0) {
                    v = fmaxf(v, 0.f);
                    _Float16 h,l; splitf(v,h,l);
                    Oh[row*NCOL + col] = h;
                    Ol[row*NCOL + col] = l;
                } else {
                    Of[row*NCOL + col] = tanhf(v);
                }
            }
    }
}

// ---------------------------------------------------------------------------
// Persistent recurrence chunk. 256 blocks x 512 thr, 1 block/CU (plain launch,
// grid == capacity). 8 panels (128 rows, panel = XCC_ID) x 32 col-slices.
// Swapped-operand MFMA; gates in-register. NEW vs r13:
//  (1) barrier_wait = spin + RAW s_barrier (no vmcnt drain) -> window loads
//      genuinely stay in flight across the barrier;
//  (2) phase-1 split at its dependency boundary: kt0..7 (h1-region) computed
//      in window-2 BEFORE waiting on barrier-2; partB (kt8..23) after.
// Accumulation order kt0->23 preserved -> absmax must reproduce 4.88e-4.
// ---------------------------------------------------------------------------
struct PArgs {
    const _Float16 *XeH, *XeL;
    _Float16 *EmH, *EmL;
    const _Float16 *W1h, *W1l, *W2h, *W2l;
    const float *b1, *b2, *wz, *noise;
    _Float16 *h1rH, *h1rL, *h2rH, *h2rL;  // rings [(CH+1)][BH]
    unsigned *zcb;                         // [NB] chunk-carry z
    float *c1g, *c2g;                      // [BH]
    unsigned *ctr;                         // [NCHUNK][CH*2][8]
    unsigned *tick;                        // [NCHUNK][8]
    int chunk;
};

__device__ __forceinline__ void barrier_arrive(unsigned* c, int tid)
{
    __syncthreads();   // drains all waves' stores (vmcnt0) before the atomic
    if (tid == 0)
        __hip_atomic_fetch_add(c, 1u, __ATOMIC_RELAXED, __HIP_MEMORY_SCOPE_AGENT);
}
// spin + RAW s_barrier: no vmcnt(0) drain -> prefetches survive the barrier
__device__ __forceinline__ void barrier_wait(unsigned* c, int tid)
{
    if (tid == 0) {
        int guard = 0;
        while (__hip_atomic_load(c, __ATOMIC_RELAXED, __HIP_MEMORY_SCOPE_AGENT) < 32u
               && guard < (1<<17)) {
            __builtin_amdgcn_s_sleep(1);
            ++guard;
        }
    }
    asm volatile("" ::: "memory");
    __builtin_amdgcn_s_barrier();
    asm volatile("" ::: "memory");
}

__global__ __launch_bounds__(512, 1)
void hm_pers_k(PArgs a)
{
    extern __shared__ __align__(16) char smem[];

    const int tid = threadIdx.x, wv = tid>>6, lane = tid&63;
    const int lr = lane&15, hq = lane>>4, kg8 = hq<<3;

    // ---- XCD-grounded panel/cs assignment ----
    unsigned* pan_sh = (unsigned*)(smem + PAN_OFF);
    if (tid == 0) {
        unsigned xcc;
        asm volatile("s_getreg_b32 %0, hwreg(HW_REG_XCC_ID)" : "=s"(xcc));
        xcc &= 7u;
        unsigned slot = __hip_atomic_fetch_add(a.tick + a.chunk*8 + xcc, 1u,
                          __ATOMIC_RELAXED, __HIP_MEMORY_SCOPE_AGENT);
        pan_sh[0] = xcc;
        pan_sh[1] = slot & 31u;
    }
    __syncthreads();
    const int panel = pan_sh[0], cs = pan_sh[1];
    const int R0 = panel*128, hb = cs*8;
    const int row = R0 + wv*16 + lr;              // batch row owned by lane
    const size_t rbase = (size_t)row*HID;
    const int hc0 = hb + hq, hc1 = hb + 4 + hq;   // owned hidden cols

    float b1v[2][4], b2v[2][4];
#pragma unroll
    for (int cf=0; cf<2; ++cf)
#pragma unroll
        for (int q=0;q<4;++q) {
            int hc = hb + cf*4 + hq;
            b1v[cf][q] = a.b1[q*256 + hc];
            b2v[cf][q] = a.b2[q*256 + hc];
        }
    const float b1z = a.b1[1024];

    // ---- stage W1 hi/lo + W2 hi + wz into LDS (once per chunk) ----
#pragma unroll
    for (int it = 0; it < 12; ++it) {
        int idx = it*512 + tid;                   // 0..6143 half8s
        int hl  = idx >= 3072;
        int e   = idx - hl*3072;
        int c   = e / 96;
        int ks  = e - c*96;
        const _Float16* src = (hl ? a.W1l : a.W1h)
            + (size_t)(cs*32 + c)*768 + ks*8;
        *(half8*)(smem + (hl ? W1L_OFF : W1H_OFF) + (c*LK1 + ks*8)*2)
            = *(const half8*)src;
    }
#pragma unroll
    for (int it = 0; it < 4; ++it) {
        int idx = it*512 + tid;                   // 0..2047
        int c   = idx >> 6;
        int ks  = idx & 63;
        const _Float16* src = a.W2h + (size_t)(cs*32 + c)*512 + ks*8;
        *(half8*)(smem + W2H_OFF + (c*LW2 + ks*8)*2) = *(const half8*)src;
    }
    {
        float* wzl = (float*)(smem + WZ_OFF);
        for (int i = tid; i < 768; i += 512) wzl[i] = a.wz[i];
    }
    __syncthreads();
    const float* wzl = (const float*)(smem + WZ_OFF);

    float c1s[2] = { a.c1g[rbase + hc0], a.c1g[rbase + hc1] };
    float c2s[2] = { a.c2g[rbase + hc0], a.c2g[rbase + hc1] };
    bool zrv = a.zcb[row] != 0u;

    const _Float16* w2lp[2] = {
        a.W2l + (size_t)(cs*32      + lr)*512 + kg8,
        a.W2l + (size_t)(cs*32 + 16 + lr)*512 + kg8
    };

    half8 pf_h[4], pf_l[4];      // rotating prefetch
    half8 xf_h[8], xf_l[8];      // xe fragments, loaded a phase early
    f32x4 am1[2], ax1[2];        // phase-1 accumulators (live across windows)
    float zacc;

    // ---- prologue: partA of step 0 (h1 region kt0..7) + xe(t0) ----
    {
        am1[0]=(f32x4)0.f; am1[1]=(f32x4)0.f;
        ax1[0]=(f32x4)0.f; ax1[1]=(f32x4)0.f; zacc = 0.f;
#pragma unroll
        for (int kt = 0; kt < 4; ++kt) {
            pf_h[kt] = *(const half8*)(a.h1rH + rbase + kt*32 + kg8);
            pf_l[kt] = *(const half8*)(a.h1rL + rbase + kt*32 + kg8);
        }
#pragma unroll
        for (int kt = 0; kt < 8; ++kt) {
            half8 sh = pf_h[kt&3], sl = pf_l[kt&3];
            if (kt+4 < 8) {
                pf_h[kt&3] = *(const half8*)(a.h1rH + rbase + (kt+4)*32 + kg8);
                pf_l[kt&3] = *(const half8*)(a.h1rL + rbase + (kt+4)*32 + kg8);
            }
#pragma unroll
            for (int i = 0; i < 8; ++i)
                zacc = fmaf((float)sh[i] + (float)sl[i]*INV2K,
                            wzl[kt*32 + kg8 + i], zacc);
#pragma unroll
            for (int cf = 0; cf < 2; ++cf) {
                const int wb = (cf*16 + lr)*LK1 + kt*32 + kg8;
                half8 wh = *(const half8*)((const _Float16*)(smem + W1H_OFF) + wb);
                half8 wl = *(const half8*)((const _Float16*)(smem + W1L_OFF) + wb);
                am1[cf] = __builtin_amdgcn_mfma_f32_16x16x32_f16(wh, sh, am1[cf],0,0,0);
                ax1[cf] = __builtin_amdgcn_mfma_f32_16x16x32_f16(wl, sh, ax1[cf],0,0,0);
                ax1[cf] = __builtin_amdgcn_mfma_f32_16x16x32_f16(wh, sl, ax1[cf],0,0,0);
            }
        }
        const _Float16* xeh0 = a.XeH + (size_t)(a.chunk*CH)*BH;
        const _Float16* xel0 = a.XeL + (size_t)(a.chunk*CH)*BH;
#pragma unroll
        for (int j = 0; j < 8; ++j) {
            xf_h[j] = *(const half8*)(xeh0 + rbase + j*32 + kg8);
            xf_l[j] = *(const half8*)(xel0 + rbase + j*32 + kg8);
        }
    }

#pragma unroll 1
    for (int s = 0; s < CH; ++s) {
        const int t = a.chunk*CH + s;
        const _Float16* h1cH = a.h1rH + (size_t)s*BH;
        const _Float16* h1cL = a.h1rL + (size_t)s*BH;
        _Float16*       h1nH = a.h1rH + (size_t)(s+1)*BH;
        _Float16*       h1nL = a.h1rL + (size_t)(s+1)*BH;
        const _Float16* h2cH = a.h2rH + (size_t)s*BH;
        const _Float16* h2cL = a.h2rL + (size_t)s*BH;
        _Float16*       h2nH = a.h2rH + (size_t)(s+1)*BH;
        _Float16*       h2nL = a.h2rL + (size_t)(s+1)*BH;

        auto ld1b = [&](int kt, half8& h, half8& l){   // partB h2-region kt 8..15
            const int k0 = kt*32;
            h = *(const half8*)(h2cH + rbase + (k0-256) + kg8);
            l = *(const half8*)(h2cL + rbase + (k0-256) + kg8);
        };
        auto ld2 = [&](int kt, half8& h, half8& l){
            const int k0 = kt*32;
            if (k0 < 256) { h = *(const half8*)(h2cH + rbase + k0 + kg8);
                            l = *(const half8*)(h2cL + rbase + k0 + kg8); }
            else          { h = *(const half8*)(h1nH + rbase + (k0-256) + kg8);
                            l = *(const half8*)(h1nL + rbase + (k0-256) + kg8); }
        };

        // wait for barrier-2 of step s-1: h2c(s) = h2n(s-1) now complete
        if (s > 0)
            barrier_wait(a.ctr + ((size_t)(a.chunk*CH + s-1)*2 + 1)*8 + panel, tid);

        // ============ phase 1 partB: kt8..23 (z*h2 | xe) ====================
#pragma unroll
        for (int kt = 8; kt < 12; ++kt) ld1b(kt, pf_h[kt&3], pf_l[kt&3]);
#pragma unroll
        for (int kt = 8; kt < 24; ++kt) {
            half8 sh, sl;
            if (kt < 16) {
                sh = pf_h[kt&3]; sl = pf_l[kt&3];
                if (kt+4 < 16) ld1b(kt+4, pf_h[kt&3], pf_l[kt&3]);
                if (!zrv) { sh = half8{}; sl = half8{}; }
            } else {
                sh = xf_h[kt-16]; sl = xf_l[kt-16];
            }
#pragma unroll
            for (int i = 0; i < 8; ++i)
                zacc = fmaf((float)sh[i] + (float)sl[i]*INV2K,
                            wzl[kt*32 + kg8 + i], zacc);
#pragma unroll
            for (int cf = 0; cf < 2; ++cf) {
                const int wb = (cf*16 + lr)*LK1 + kt*32 + kg8;
                half8 wh = *(const half8*)((const _Float16*)(smem + W1H_OFF) + wb);
                half8 wl = *(const half8*)((const _Float16*)(smem + W1L_OFF) + wb);
                am1[cf] = __builtin_amdgcn_mfma_f32_16x16x32_f16(wh, sh, am1[cf],0,0,0);
                ax1[cf] = __builtin_amdgcn_mfma_f32_16x16x32_f16(wl, sh, ax1[cf],0,0,0);
                ax1[cf] = __builtin_amdgcn_mfma_f32_16x16x32_f16(wh, sl, ax1[cf],0,0,0);
            }
        }
        zacc += __shfl_xor(zacc, 16);
        zacc += __shfl_xor(zacc, 32);

        float fsz = zacc + b1z;
        float zh = fminf(fmaxf((0.1f*fsz + 1.f)*0.5f, 0.05f), 0.95f);
        const bool znv = a.noise[(size_t)t*NB + row] < zh;

        // in-register gate combine + h1 update (q = gate)
#pragma unroll
        for (int cf = 0; cf < 2; ++cf) {
            float v0 = am1[cf][0] + ax1[cf][0]*INV2K + b1v[cf][0];
            float v1 = am1[cf][1] + ax1[cf][1]*INV2K + b1v[cf][1];
            float v2 = am1[cf][2] + ax1[cf][2]*INV2K + b1v[cf][2];
            float v3 = am1[cf][3] + ax1[cf][3]*INV2K + b1v[cf][3];
            float f = sigf(v0), i = sigf(v1), o = sigf(v2), g = tanhf(v3);
            float cn = f*c1s[cf] + i*g;
            c1s[cf] = cn;
            float hn = o*tanhf(cn);
            _Float16 hh, hl; splitf(hn, hh, hl);
            const int hc = (cf==0) ? hc0 : hc1;
            h1nH[rbase + hc] = hh; h1nL[rbase + hc] = hl;
            if (s == CH-1) { a.h1rH[rbase + hc] = hh; a.h1rL[rbase + hc] = hl; }
        }
        if (s == CH-1 && hq == 0) a.zcb[row] = znv ? 1u : 0u;

        unsigned* b1c = a.ctr + ((size_t)(a.chunk*CH + s)*2 + 0)*8 + panel;
        barrier_arrive(b1c, tid);

        // -------- window 1: phase2a h2-region (legal: h2c from step s-1) ----
        f32x4 am2[2], ax2[2];
        am2[0]=(f32x4)0.f; am2[1]=(f32x4)0.f;
        ax2[0]=(f32x4)0.f; ax2[1]=(f32x4)0.f;
#pragma unroll
        for (int kt = 0; kt < 4; ++kt) ld2(kt, pf_h[kt], pf_l[kt]);
#pragma unroll
        for (int kt = 0; kt < 8; ++kt) {
            half8 sh = pf_h[kt&3], sl = pf_l[kt&3];
            if (kt+4 < 8) ld2(kt+4, pf_h[kt&3], pf_l[kt&3]);
#pragma unroll
            for (int cf = 0; cf < 2; ++cf) {
                const int wb = (cf*16 + lr)*LW2 + kt*32 + kg8;
                half8 wh = *(const half8*)((const _Float16*)(smem + W2H_OFF) + wb);
                half8 wl = *(const half8*)(w2lp[cf] + kt*32);
                am2[cf] = __builtin_amdgcn_mfma_f32_16x16x32_f16(wh, sh, am2[cf],0,0,0);
                ax2[cf] = __builtin_amdgcn_mfma_f32_16x16x32_f16(wl, sh, ax2[cf],0,0,0);
                ax2[cf] = __builtin_amdgcn_mfma_f32_16x16x32_f16(wh, sl, ax2[cf],0,0,0);
            }
        }
        barrier_wait(b1c, tid);

        // -------- phase 2b: h1n-region (needs all blocks' h1n) --------------
#pragma unroll
        for (int kt = 8; kt < 12; ++kt) ld2(kt, pf_h[kt&3], pf_l[kt&3]);
#pragma unroll
        for (int kt = 8; kt < 16; ++kt) {
            half8 sh = pf_h[kt&3], sl = pf_l[kt&3];
            if (kt+4 < 16) ld2(kt+4, pf_h[kt&3], pf_l[kt&3]);
            if (!znv) { sh = half8{}; sl = half8{}; }
#pragma unroll
            for (int cf = 0; cf < 2; ++cf) {
                const int wb = (cf*16 + lr)*LW2 + kt*32 + kg8;
                half8 wh = *(const half8*)((const _Float16*)(smem + W2H_OFF) + wb);
                half8 wl = *(const half8*)(w2lp[cf] + kt*32);
                am2[cf] = __builtin_amdgcn_mfma_f32_16x16x32_f16(wh, sh, am2[cf],0,0,0);
                ax2[cf] = __builtin_amdgcn_mfma_f32_16x16x32_f16(wl, sh, ax2[cf],0,0,0);
                ax2[cf] = __builtin_amdgcn_mfma_f32_16x16x32_f16(wh, sl, ax2[cf],0,0,0);
            }
        }

        // epilogue 2 (in-register; znv is per-lane-row)
#pragma unroll
        for (int cf = 0; cf < 2; ++cf) {
            float v0 = am2[cf][0] + ax2[cf][0]*INV2K + b2v[cf][0];
            float v1 = am2[cf][1] + ax2[cf][1]*INV2K + b2v[cf][1];
            float v2 = am2[cf][2] + ax2[cf][2]*INV2K + b2v[cf][2];
            float v3 = am2[cf][3] + ax2[cf][3]*INV2K + b2v[cf][3];
            float f = sigf(v0), i = sigf(v1), o = sigf(v2), g = tanhf(v3);
            float cn = znv ? (f*c2s[cf] + i*g) : c2s[cf];
            c2s[cf] = cn;
            float hn = o*tanhf(cn);
            _Float16 hh, hl; splitf(hn, hh, hl);
            const int hc = (cf==0) ? hc0 : hc1;
            h2nH[rbase + hc] = hh; h2nL[rbase + hc] = hl;
            a.EmH[(size_t)t*BH + rbase + hc] = hh;
            a.EmL[(size_t)t*BH + rbase + hc] = hl;
            if (s == CH-1) { a.h2rH[rbase + hc] = hh; a.h2rL[rbase + hc] = hl; }
        }
        zrv = znv;   // carry z in-register to next step

        unsigned* b2c = a.ctr + ((size_t)(a.chunk*CH + s)*2 + 1)*8 + panel;
        barrier_arrive(b2c, tid);

        // -------- window 2: phase-1(s+1) partA (h1 kt0..7, legal after b1c) +
        //          xe(t+1) prefetch; wait for b2c deferred to next iteration --
        if (s+1 < CH) {
            am1[0]=(f32x4)0.f; am1[1]=(f32x4)0.f;
            ax1[0]=(f32x4)0.f; ax1[1]=(f32x4)0.f; zacc = 0.f;
#pragma unroll
            for (int kt = 0; kt < 4; ++kt) {
                pf_h[kt] = *(const half8*)(h1nH + rbase + kt*32 + kg8);
                pf_l[kt] = *(const half8*)(h1nL + rbase + kt*32 + kg8);
            }
#pragma unroll
            for (int kt = 0; kt < 8; ++kt) {
                half8 sh = pf_h[kt&3], sl = pf_l[kt&3];
                if (kt+4 < 8) {
                    pf_h[kt&3] = *(const half8*)(h1nH + rbase + (kt+4)*32 + kg8);
                    pf_l[kt&3] = *(const half8*)(h1nL + rbase + (kt+4)*32 + kg8);
                }
#pragma unroll
                for (int i = 0; i < 8; ++i)
                    zacc = fmaf((float)sh[i] + (float)sl[i]*INV2K,
                                wzl[kt*32 + kg8 + i], zacc);
#pragma unroll
                for (int cf = 0; cf < 2; ++cf) {
                    const int wb = (cf*16 + lr)*LK1 + kt*32 + kg8;
                    half8 wh = *(const half8*)((const _Float16*)(smem + W1H_OFF) + wb);
                    half8 wl = *(const half8*)((const _Float16*)(smem + W1L_OFF) + wb);
                    am1[cf] = __builtin_amdgcn_mfma_f32_16x16x32_f16(wh, sh, am1[cf],0,0,0);
                    ax1[cf] = __builtin_amdgcn_mfma_f32_16x16x32_f16(wl, sh, ax1[cf],0,0,0);
                    ax1[cf] = __builtin_amdgcn_mfma_f32_16x16x32_f16(wh, sl, ax1[cf],0,0,0);
                }
            }
            const _Float16* xehn = a.XeH + (size_t)(t+1)*BH;
            const _Float16* xeln = a.XeL + (size_t)(t+1)*BH;
#pragma unroll
            for (int j = 0; j < 8; ++j) {
                xf_h[j] = *(const half8*)(xehn + rbase + j*32 + kg8);
                xf_l[j] = *(const half8*)(xeln + rbase + j*32 + kg8);
            }
        }
    }

    // carry c across chunk boundary
    a.c1g[rbase + hc0] = c1s[0]; a.c1g[rbase + hc1] = c1s[1];
    a.c2g[rbase + hc0] = c2s[0]; a.c2g[rbase + hc1] = c2s[1];
}

// ---------------------------------------------------------------------------
extern "C" void kernel_launch(void* const* d_in, const int* in_sizes, int n_in,
                              void* d_out, int out_size, void* d_ws, size_t ws_size,
                              hipStream_t stream)
{
    const float* x     = (const float*)d_in[0];
    const float* n1    = (const float*)d_in[1];
    const float* We1   = (const float*)d_in[3];
    const float* be1   = (const float*)d_in[4];
    const float* We2   = (const float*)d_in[5];
    const float* be2   = (const float*)d_in[6];
    const float* U11_1 = (const float*)d_in[7];
    const float* U21_1 = (const float*)d_in[8];
    const float* W01_1 = (const float*)d_in[9];
    const float* b1    = (const float*)d_in[10];
    const float* U11_2 = (const float*)d_in[11];
    const float* W01_2 = (const float*)d_in[12];
    const float* b2    = (const float*)d_in[13];
    const float* Wh    = (const float*)d_in[14];
    const float* bh    = (const float*)d_in[15];
    const float* Wp    = (const float*)d_in[16];
    const float* bp_   = (const float*)d_in[17];
    float* out = (float*)d_out;

    char* p = (char*)d_ws;
    auto alloc = [&](size_t bytes){ char* q = p; p += (bytes + 255) & ~(size_t)255; return q; };
    _Float16* XeH  = (_Float16*)alloc((size_t)NSTEP*BH*2);
    _Float16* XeL  = (_Float16*)alloc((size_t)NSTEP*BH*2);
    _Float16* EmH  = (_Float16*)alloc((size_t)NSTEP*BH*2);
    _Float16* EmL  = (_Float16*)alloc((size_t)NSTEP*BH*2);
    _Float16* Wt1h = (_Float16*)alloc((size_t)1024*768*2);
    _Float16* Wt1l = (_Float16*)alloc((size_t)1024*768*2);
    _Float16* Wt2h = (_Float16*)alloc((size_t)1024*512*2);
    _Float16* Wt2l = (_Float16*)alloc((size_t)1024*512*2);
    _Float16* We1h = (_Float16*)alloc(256*256*2);
    _Float16* We1l = (_Float16*)alloc(256*256*2);
    _Float16* We2h = (_Float16*)alloc(256*256*2);
    _Float16* We2l = (_Float16*)alloc(256*256*2);
    _Float16* Whh  = (_Float16*)alloc(256*256*2);
    _Float16* Whl  = (_Float16*)alloc(256*256*2);
    _Float16* Wph  = (_Float16*)alloc(64*256*2);
    _Float16* Wpl  = (_Float16*)alloc(64*256*2);
    float*    wz1  = (float*)alloc(768*4);
    _Float16* h1rH = (_Float16*)alloc((size_t)(CH+1)*BH*2);
    _Float16* h1rL = (_Float16*)alloc((size_t)(CH+1)*BH*2);
    _Float16* h2rH = (_Float16*)alloc((size_t)(CH+1)*BH*2);
    _Float16* h2rL = (_Float16*)alloc((size_t)(CH+1)*BH*2);
    unsigned* zcb  = (unsigned*)alloc(NB*4);
    float*    c1g  = (float*)alloc((size_t)BH*4);
    float*    c2g  = (float*)alloc((size_t)BH*4);
    unsigned* ctr  = (unsigned*)alloc((size_t)NCHUNK*CH*2*8*4);
    unsigned* tick = (unsigned*)alloc((size_t)NCHUNK*8*4);
    if (ws_size < (size_t)(p - (char*)d_ws)) return;

    _Float16* TmpH = EmH; _Float16* TmpL = EmL;   // encoder temp (Em dead then)
    _Float16* TpH  = XeH; _Float16* TpL  = XeL;   // head temp (Xe dead then)

    // ---- prep ----
    wsplit_k<<<dim3(3072), 256, 0, stream>>>(W01_1, U21_1, U11_1, 768, 1024, 1025, 256, 512, 1, Wt1h, Wt1l);
    wsplit_k<<<dim3(2048), 256, 0, stream>>>(W01_2, U11_2, nullptr, 512, 1024, 1025, 256, 512, 1, Wt2h, Wt2l);
    wsplit_k<<<dim3(256),  256, 0, stream>>>(We1, nullptr, nullptr, 256, 256, 256, 256, 256, 0, We1h, We1l);
    wsplit_k<<<dim3(256),  256, 0, stream>>>(We2, nullptr, nullptr, 256, 256, 256, 256, 256, 0, We2h, We2l);
    wsplit_k<<<dim3(256),  256, 0, stream>>>(Wh,  nullptr, nullptr, 256, 256, 256, 256, 256, 0, Whh,  Whl);
    wsplit_k<<<dim3(64),   256, 0, stream>>>(Wp,  nullptr, nullptr, 256, 64, 64, 256, 256, 0, Wph, Wpl);
    wz_k<<<dim3(3), 256, 0, stream>>>(W01_1, U21_1, U11_1, wz1);
    init_k<<<dim3(1024), 256, 0, stream>>>(h1rH, h1rL, h2rH, h2rL, c1g, c2g, zcb);
    (void)hipMemsetAsync(ctr, 0, (size_t)NCHUNK*CH*2*8*4, stream);
    (void)hipMemsetAsync(tick, 0, (size_t)NCHUNK*8*4, stream);

    // ---- encoder: xe = relu(relu(x@We1)@We2) -> Xe ----
    for (int c = 0; c < 8; ++c) {
        size_t ro = (size_t)c*32*BH;
        gemm_t<0,0,256><<<dim3(512,4), 256, 0, stream>>>(
            x + ro, nullptr, nullptr, We1h, We1l, be1, TmpH, TmpL, nullptr);
        gemm_t<1,0,256><<<dim3(512,4), 256, 0, stream>>>(
            nullptr, TmpH, TmpL, We2h, We2l, be2, XeH + ro, XeL + ro, nullptr);
    }

    // ---- recurrence: 8 persistent chunks, plain launch (grid == capacity) ----
    (void)hipFuncSetAttribute((const void*)hm_pers_k,
        hipFuncAttributeMaxDynamicSharedMemorySize, SEQ_SMEM);
    PArgs pa;
    pa.XeH = XeH; pa.XeL = XeL; pa.EmH = EmH; pa.EmL = EmL;
    pa.W1h = Wt1h; pa.W1l = Wt1l; pa.W2h = Wt2h; pa.W2l = Wt2l;
    pa.b1 = b1; pa.b2 = b2; pa.wz = wz1; pa.noise = n1;
    pa.h1rH = h1rH; pa.h1rL = h1rL; pa.h2rH = h2rH; pa.h2rL = h2rL;
    pa.zcb = zcb; pa.c1g = c1g; pa.c2g = c2g; pa.ctr = ctr; pa.tick = tick;
    for (int c = 0; c < NCHUNK; ++c) {
        pa.chunk = c;
        hm_pers_k<<<dim3(256), dim3(512), SEQ_SMEM, stream>>>(pa);
    }

    // ---- head: out = tanh(relu(emb@Wh)@Wp) ----
    for (int c = 0; c < 8; ++c) {
        size_t ro = (size_t)c*32*BH;
        gemm_t<1,0,256><<<dim3(512,4), 256, 0, stream>>>(
            nullptr, EmH + ro, EmL + ro, Whh, Whl, bh, TpH, TpL, nullptr);
        gemm_t<1,1,64><<<dim3(512,1), 256, 0, stream>>>(
            nullptr, TpH, TpL, Wph, Wpl, bp_, nullptr, nullptr,
            out + (size_t)c*32*NB*64);
    }
}